// Round 8
// baseline (148.042 us; speedup 1.0000x reference)
//
#include <hip/hip_runtime.h>
#include <math.h>

#define HPIX 160
#define WPIX 160
#define NPIX 25600      // 160*160
#define C0   128
#define CM   64
#define MID  16
#define KK   11
#define KK2  121
#define PAD  5
#define PADW 176        // 160 + 2*5, rounded up to 16 for row alignment
#define PADH 170
#define CHP  (PADH*PADW)   // 29920 floats per padded channel
#define NBX  (NPIX/256)    // 100 pixel-blocks for conv kernels
#define BN_EPS 1e-5f

__device__ __forceinline__ float elu_f(float y) { return y > 0.f ? y : expm1f(y); }

// ---------------- act = elu(bn1(x)), vectorized float4 ----------------
__global__ __launch_bounds__(256) void k_act(
        const float* __restrict__ x,
        const float* __restrict__ g1, const float* __restrict__ b1,
        const float* __restrict__ m1, const float* __restrict__ v1,
        float* __restrict__ act) {
    int i4 = blockIdx.x * 256 + threadIdx.x;
    int c = i4 / (NPIX / 4);
    float inv  = g1[c] * rsqrtf(v1[c] + BN_EPS);
    float beta = b1[c] - m1[c] * inv;
    float4 xv = ((const float4*)x)[i4];
    float4 o;
    o.x = elu_f(fmaf(xv.x, inv, beta));
    o.y = elu_f(fmaf(xv.y, inv, beta));
    o.z = elu_f(fmaf(xv.z, inv, beta));
    o.w = elu_f(fmaf(xv.w, inv, beta));
    ((float4*)act)[i4] = o;
}

// ---------------- conv1: act -> elu(bn2(w1 @ act)) into padded feat ----
// grid (NBX, CM/16), block 256. Thread: 1 pixel, 16 oc. float4 weight loads.
__global__ __launch_bounds__(256, 4) void k_conv1(
        const float* __restrict__ act, const float* __restrict__ w1,
        const float* __restrict__ g2, const float* __restrict__ b2,
        const float* __restrict__ m2, const float* __restrict__ v2,
        float* __restrict__ feat_pad) {
    const int tid = threadIdx.x;
    const int p   = blockIdx.x * 256 + tid;
    const int oc0 = blockIdx.y * 16;
    const float* wbase = w1 + oc0 * C0;

    float acc[16] = {0,0,0,0,0,0,0,0,0,0,0,0,0,0,0,0};
    #pragma unroll 2
    for (int k0 = 0; k0 < C0; k0 += 4) {
        float a0 = act[(k0 + 0) * NPIX + p];
        float a1 = act[(k0 + 1) * NPIX + p];
        float a2 = act[(k0 + 2) * NPIX + p];
        float a3 = act[(k0 + 3) * NPIX + p];
        #pragma unroll
        for (int j = 0; j < 16; ++j) {
            float4 wv = *(const float4*)(wbase + j * C0 + k0);
            acc[j] = fmaf(wv.x, a0, acc[j]);
            acc[j] = fmaf(wv.y, a1, acc[j]);
            acc[j] = fmaf(wv.z, a2, acc[j]);
            acc[j] = fmaf(wv.w, a3, acc[j]);
        }
    }

    const int h = p / WPIX, w = p % WPIX;
    const int off = (h + PAD) * PADW + (w + PAD);
    #pragma unroll
    for (int j = 0; j < 16; ++j) {
        int c = oc0 + j;
        float inv = g2[c] * rsqrtf(v2[c] + BN_EPS);
        float y = acc[j] * inv + (b2[c] - m2[c] * inv);
        feat_pad[c * CHP + off] = elu_f(y);
    }
}

// ---------------- conv_t: feat_pad -> t = relu(bn(inv_w1 @ feat)) -----------
// grid (NBX, MID/4), block 256. Thread: 1 pixel, 4 oc. float4 weight loads.
__global__ __launch_bounds__(256, 4) void k_conv_t(
        const float* __restrict__ feat_pad, const float* __restrict__ wt,
        const float* __restrict__ g, const float* __restrict__ b,
        const float* __restrict__ m, const float* __restrict__ v,
        float* __restrict__ t) {
    const int tid = threadIdx.x;
    const int p   = blockIdx.x * 256 + tid;
    const int oc0 = blockIdx.y * 4;
    const int h = p / WPIX, w = p % WPIX;
    const int off = (h + PAD) * PADW + (w + PAD);

    float acc[4] = {0,0,0,0};
    #pragma unroll 4
    for (int k0 = 0; k0 < CM; k0 += 4) {
        float a0 = feat_pad[(k0 + 0) * CHP + off];
        float a1 = feat_pad[(k0 + 1) * CHP + off];
        float a2 = feat_pad[(k0 + 2) * CHP + off];
        float a3 = feat_pad[(k0 + 3) * CHP + off];
        #pragma unroll
        for (int j = 0; j < 4; ++j) {
            float4 wv = *(const float4*)(wt + (oc0 + j) * CM + k0);
            acc[j] = fmaf(wv.x, a0, acc[j]);
            acc[j] = fmaf(wv.y, a1, acc[j]);
            acc[j] = fmaf(wv.z, a2, acc[j]);
            acc[j] = fmaf(wv.w, a3, acc[j]);
        }
    }
    #pragma unroll
    for (int j = 0; j < 4; ++j) {
        int c = oc0 + j;
        float inv = g[c] * rsqrtf(v[c] + BN_EPS);
        t[c * NPIX + p] = fmaxf(acc[j] * inv + (b[c] - m[c] * inv), 0.f);
    }
}

// ---------------- involution: wk-gen + 11x11 weighted sum + bn3 + elu -------
// Block 128 threads, covers 16 px (one row) x 64 channels.
// Phase 3: thread = 4 px x 2 channels (same group) -> each wk ds_read_b128
// feeds 8 FMAs (was 4), halving LDS-pipe demand.
__global__ __launch_bounds__(128, 4) void k_involution(
        const float* __restrict__ t, const float* __restrict__ feat_pad,
        const float* __restrict__ inv_w2, const float* __restrict__ inv_b2,
        const float* __restrict__ g3, const float* __restrict__ b3,
        const float* __restrict__ m3, const float* __restrict__ v3,
        float* __restrict__ out) {
    __shared__ float s_wk[484 * 16];   // [j][px], ~31 KB
    __shared__ float s_t[MID * 16];

    // T1 XCD swizzle: gridDim.x = 1600 (divisible by 8) -> bijective.
    const int q   = gridDim.x >> 3;
    const int b   = blockIdx.x;
    const int bid = (b & 7) * q + (b >> 3);

    const int tid = threadIdx.x;      // 0..127
    const int p0  = bid * 16;         // 16 consecutive px, same image row
    const int px  = tid & 15;

    s_t[tid]       = t[(tid >> 4) * NPIX + p0 + (tid & 15)];
    s_t[tid + 128] = t[((tid >> 4) + 8) * NPIX + p0 + (tid & 15)];
    __syncthreads();

    // ---- phase 2: wk[j][px]; 2 j's per iter (j, j+8), scalars only.
    {
        float tr0  = s_t[0*16+px],  tr1  = s_t[1*16+px];
        float tr2  = s_t[2*16+px],  tr3  = s_t[3*16+px];
        float tr4  = s_t[4*16+px],  tr5  = s_t[5*16+px];
        float tr6  = s_t[6*16+px],  tr7  = s_t[7*16+px];
        float tr8  = s_t[8*16+px],  tr9  = s_t[9*16+px];
        float tr10 = s_t[10*16+px], tr11 = s_t[11*16+px];
        float tr12 = s_t[12*16+px], tr13 = s_t[13*16+px];
        float tr14 = s_t[14*16+px], tr15 = s_t[15*16+px];
        const int jb = tid >> 4;      // 0..7

        for (int j = jb; j + 8 < 484; j += 16) {
            const float4* wa = (const float4*)(inv_w2 + j * MID);
            const float4* wc = (const float4*)(inv_w2 + (j + 8) * MID);
            float4 a0 = wa[0], a1 = wa[1], a2 = wa[2], a3 = wa[3];
            float4 c0 = wc[0], c1 = wc[1], c2 = wc[2], c3 = wc[3];
            float aL = inv_b2[j],     aH = 0.f;
            float cL = inv_b2[j + 8], cH = 0.f;
            aL = fmaf(a0.x, tr0, aL);  aL = fmaf(a0.y, tr1, aL);
            aL = fmaf(a0.z, tr2, aL);  aL = fmaf(a0.w, tr3, aL);
            aL = fmaf(a1.x, tr4, aL);  aL = fmaf(a1.y, tr5, aL);
            aL = fmaf(a1.z, tr6, aL);  aL = fmaf(a1.w, tr7, aL);
            aH = fmaf(a2.x, tr8, aH);  aH = fmaf(a2.y, tr9, aH);
            aH = fmaf(a2.z, tr10, aH); aH = fmaf(a2.w, tr11, aH);
            aH = fmaf(a3.x, tr12, aH); aH = fmaf(a3.y, tr13, aH);
            aH = fmaf(a3.z, tr14, aH); aH = fmaf(a3.w, tr15, aH);
            cL = fmaf(c0.x, tr0, cL);  cL = fmaf(c0.y, tr1, cL);
            cL = fmaf(c0.z, tr2, cL);  cL = fmaf(c0.w, tr3, cL);
            cL = fmaf(c1.x, tr4, cL);  cL = fmaf(c1.y, tr5, cL);
            cL = fmaf(c1.z, tr6, cL);  cL = fmaf(c1.w, tr7, cL);
            cH = fmaf(c2.x, tr8, cH);  cH = fmaf(c2.y, tr9, cH);
            cH = fmaf(c2.z, tr10, cH); cH = fmaf(c2.w, tr11, cH);
            cH = fmaf(c3.x, tr12, cH); cH = fmaf(c3.y, tr13, cH);
            cH = fmaf(c3.z, tr14, cH); cH = fmaf(c3.w, tr15, cH);
            s_wk[j * 16 + px]       = aL + aH;
            s_wk[(j + 8) * 16 + px] = cL + cH;
        }
        if (jb < 4) {                 // tail j = 480..483
            int j = 480 + jb;
            const float4* wa = (const float4*)(inv_w2 + j * MID);
            float4 a0 = wa[0], a1 = wa[1], a2 = wa[2], a3 = wa[3];
            float aL = inv_b2[j], aH = 0.f;
            aL = fmaf(a0.x, tr0, aL);  aL = fmaf(a0.y, tr1, aL);
            aL = fmaf(a0.z, tr2, aL);  aL = fmaf(a0.w, tr3, aL);
            aL = fmaf(a1.x, tr4, aL);  aL = fmaf(a1.y, tr5, aL);
            aL = fmaf(a1.z, tr6, aL);  aL = fmaf(a1.w, tr7, aL);
            aH = fmaf(a2.x, tr8, aH);  aH = fmaf(a2.y, tr9, aH);
            aH = fmaf(a2.z, tr10, aH); aH = fmaf(a2.w, tr11, aH);
            aH = fmaf(a3.x, tr12, aH); aH = fmaf(a3.y, tr13, aH);
            aH = fmaf(a3.z, tr14, aH); aH = fmaf(a3.w, tr15, aH);
            s_wk[j * 16 + px] = aL + aH;
        }
    }
    __syncthreads();

    // ---- phase 3: thread = (tx px-quad, channel PAIR). One wk read -> 8 FMA.
    const int tx = tid & 3;
    const int cp = tid >> 2;          // 0..31
    const int c0 = cp * 2;
    const int g  = c0 >> 4;
    const int h  = p0 / WPIX;
    const int wb = (p0 % WPIX) + tx * 4;
    const float* f0b = feat_pad + c0 * CHP + h * PADW + wb;
    const float* f1b = f0b + CHP;
    const float* wkb = s_wk + (g * KK2) * 16 + tx * 4;

    float a00 = 0.f, a01 = 0.f, a02 = 0.f, a03 = 0.f;
    float a10 = 0.f, a11 = 0.f, a12 = 0.f, a13 = 0.f;
    #pragma unroll 2
    for (int kh = 0; kh < KK; ++kh) {
        const float4* p0f = (const float4*)(f0b + kh * PADW);
        float4 A0 = p0f[0], B0 = p0f[1], Cq0 = p0f[2], D0 = p0f[3];
        const float4* p1f = (const float4*)(f1b + kh * PADW);
        float4 A1 = p1f[0], B1 = p1f[1], Cq1 = p1f[2], D1 = p1f[3];
        float f0[16] = {A0.x,A0.y,A0.z,A0.w, B0.x,B0.y,B0.z,B0.w,
                        Cq0.x,Cq0.y,Cq0.z,Cq0.w, D0.x,D0.y,D0.z,D0.w};
        float f1[16] = {A1.x,A1.y,A1.z,A1.w, B1.x,B1.y,B1.z,B1.w,
                        Cq1.x,Cq1.y,Cq1.z,Cq1.w, D1.x,D1.y,D1.z,D1.w};
        const float* wr = wkb + kh * KK * 16;
        #pragma unroll
        for (int kw = 0; kw < KK; ++kw) {
            float4 wv = *(const float4*)(wr + kw * 16);
            a00 = fmaf(wv.x, f0[kw + 0], a00);
            a01 = fmaf(wv.y, f0[kw + 1], a01);
            a02 = fmaf(wv.z, f0[kw + 2], a02);
            a03 = fmaf(wv.w, f0[kw + 3], a03);
            a10 = fmaf(wv.x, f1[kw + 0], a10);
            a11 = fmaf(wv.y, f1[kw + 1], a11);
            a12 = fmaf(wv.z, f1[kw + 2], a12);
            a13 = fmaf(wv.w, f1[kw + 3], a13);
        }
    }

    {
        float inv  = g3[c0] * rsqrtf(v3[c0] + BN_EPS);
        float beta = b3[c0] - m3[c0] * inv;
        float4 o;
        o.x = elu_f(fmaf(a00, inv, beta));
        o.y = elu_f(fmaf(a01, inv, beta));
        o.z = elu_f(fmaf(a02, inv, beta));
        o.w = elu_f(fmaf(a03, inv, beta));
        *(float4*)(out + c0 * NPIX + p0 + tx * 4) = o;
    }
    {
        int c1 = c0 + 1;
        float inv  = g3[c1] * rsqrtf(v3[c1] + BN_EPS);
        float beta = b3[c1] - m3[c1] * inv;
        float4 o;
        o.x = elu_f(fmaf(a10, inv, beta));
        o.y = elu_f(fmaf(a11, inv, beta));
        o.z = elu_f(fmaf(a12, inv, beta));
        o.w = elu_f(fmaf(a13, inv, beta));
        *(float4*)(out + c1 * NPIX + p0 + tx * 4) = o;
    }
}

// ---------------- conv3: buf5 -> buf6 (64 -> 128) + deterministic partials --
// grid (NBX, C0/16). Thread: 1 pixel, 16 oc. float4 weight loads.
__global__ __launch_bounds__(256, 4) void k_conv3(
        const float* __restrict__ in, const float* __restrict__ w,
        float* __restrict__ out, float* __restrict__ parts) {
    const int tid = threadIdx.x;
    const int p   = blockIdx.x * 256 + tid;
    const int oc0 = blockIdx.y * 16;
    const float* wbase = w + oc0 * CM;

    float acc[16] = {0,0,0,0,0,0,0,0,0,0,0,0,0,0,0,0};
    #pragma unroll 2
    for (int k0 = 0; k0 < CM; k0 += 4) {
        float a0 = in[(k0 + 0) * NPIX + p];
        float a1 = in[(k0 + 1) * NPIX + p];
        float a2 = in[(k0 + 2) * NPIX + p];
        float a3 = in[(k0 + 3) * NPIX + p];
        #pragma unroll
        for (int j = 0; j < 16; ++j) {
            float4 wv = *(const float4*)(wbase + j * CM + k0);
            acc[j] = fmaf(wv.x, a0, acc[j]);
            acc[j] = fmaf(wv.y, a1, acc[j]);
            acc[j] = fmaf(wv.z, a2, acc[j]);
            acc[j] = fmaf(wv.w, a3, acc[j]);
        }
    }
    #pragma unroll
    for (int j = 0; j < 16; ++j)
        out[(oc0 + j) * NPIX + p] = acc[j];

    __shared__ float s_red[16][4];
    const int lane = tid & 63, wid = tid >> 6;
    #pragma unroll
    for (int j = 0; j < 16; ++j) {
        float s = acc[j];
        #pragma unroll
        for (int off = 32; off; off >>= 1) s += __shfl_down(s, off);
        if (lane == 0) s_red[j][wid] = s;
    }
    __syncthreads();
    if (tid < 16) {
        float s = s_red[tid][0] + s_red[tid][1] + s_red[tid][2] + s_red[tid][3];
        parts[(oc0 + tid) * NBX + blockIdx.x] = s;   // deterministic write
    }
}

// ---------------- SE MLP: reduce partials -> 128->8 relu -> 8->128 sigmoid --
__global__ void k_se(const float* __restrict__ parts,
                     const float* __restrict__ w1, const float* __restrict__ b1,
                     const float* __restrict__ w2, const float* __restrict__ b2,
                     float* __restrict__ scale) {
    __shared__ float s_p[C0];
    __shared__ float s_h[8];
    int tid = threadIdx.x;
    float s = 0.f;
    for (int i = 0; i < NBX; ++i) s += parts[tid * NBX + i];  // fixed order
    s_p[tid] = s * (1.f / NPIX);
    __syncthreads();
    if (tid < 8) {
        float acc = b1[tid];
        for (int c = 0; c < C0; ++c) acc = fmaf(w1[tid * C0 + c], s_p[c], acc);
        s_h[tid] = fmaxf(acc, 0.f);
    }
    __syncthreads();
    float acc = b2[tid];
    #pragma unroll
    for (int j = 0; j < 8; ++j) acc = fmaf(w2[tid * 8 + j], s_h[j], acc);
    scale[tid] = 1.f / (1.f + expf(-acc));
}

// ---------------- Final: out = pre * scale[c] + x, float4 ----------------
__global__ __launch_bounds__(256) void k_final(
        const float* __restrict__ pre, const float* __restrict__ scale,
        const float* __restrict__ x, float* __restrict__ out) {
    int i4 = blockIdx.x * 256 + threadIdx.x;
    int c = i4 / (NPIX / 4);
    float sc = scale[c];
    float4 pv = ((const float4*)pre)[i4];
    float4 xv = ((const float4*)x)[i4];
    float4 o;
    o.x = fmaf(pv.x, sc, xv.x);
    o.y = fmaf(pv.y, sc, xv.y);
    o.z = fmaf(pv.z, sc, xv.z);
    o.w = fmaf(pv.w, sc, xv.w);
    ((float4*)out)[i4] = o;
}

extern "C" void kernel_launch(void* const* d_in, const int* in_sizes, int n_in,
                              void* d_out, int out_size, void* d_ws, size_t ws_size,
                              hipStream_t stream) {
    const float* x      = (const float*)d_in[0];
    const float* g1     = (const float*)d_in[1];
    const float* b1     = (const float*)d_in[2];
    const float* m1     = (const float*)d_in[3];
    const float* v1     = (const float*)d_in[4];
    const float* w1     = (const float*)d_in[5];
    const float* g2     = (const float*)d_in[6];
    const float* b2     = (const float*)d_in[7];
    const float* m2     = (const float*)d_in[8];
    const float* v2     = (const float*)d_in[9];
    const float* inv_w1 = (const float*)d_in[10];
    const float* ig     = (const float*)d_in[11];
    const float* ib     = (const float*)d_in[12];
    const float* im     = (const float*)d_in[13];
    const float* iv     = (const float*)d_in[14];
    const float* inv_w2 = (const float*)d_in[15];
    const float* inv_b2 = (const float*)d_in[16];
    const float* g3     = (const float*)d_in[17];
    const float* b3     = (const float*)d_in[18];
    const float* m3     = (const float*)d_in[19];
    const float* v3     = (const float*)d_in[20];
    const float* w3     = (const float*)d_in[21];
    const float* se_w1  = (const float*)d_in[22];
    const float* se_b1  = (const float*)d_in[23];
    const float* se_w2  = (const float*)d_in[24];
    const float* se_b2  = (const float*)d_in[25];
    float* out = (float*)d_out;

    float* ws       = (float*)d_ws;
    float* act      = ws;                        // 128*25600 (elu(bn1(x)))
    float* feat_pad = act + C0 * NPIX;           // 64 * 29920 (zero-padded)
    float* buf_t    = feat_pad + CM * CHP;       // 16 * 25600
    float* buf5     = act;                       // alias: act dead after conv1
    float* buf6     = buf_t + MID * NPIX;        // 128 * 25600
    float* parts    = feat_pad;                  // alias: feat dead after invol
    float* scale    = buf6 + C0 * NPIX;          // 128

    // zero padded-feat border (every call; conv1 rewrites the interior)
    hipMemsetAsync(feat_pad, 0, (size_t)CM * CHP * sizeof(float), stream);

    // 1. act = elu(bn1(x)) once
    k_act<<<(C0 * NPIX / 4) / 256, 256, 0, stream>>>(x, g1, b1, m1, v1, act);

    // 2. conv1x1 128->64 + bn2+elu, into padded layout
    k_conv1<<<dim3(NBX, CM / 16), 256, 0, stream>>>(
        act, w1, g2, b2, m2, v2, feat_pad);

    // 3a. involution reduce: conv1x1 64->16 + bn + relu
    k_conv_t<<<dim3(NBX, MID / 4), 256, 0, stream>>>(
        feat_pad, inv_w1, ig, ib, im, iv, buf_t);

    // 3b. involution (wk-gen + weighted patch sum) + bn3 + elu, 128-thr blocks
    k_involution<<<NPIX / 16, 128, 0, stream>>>(buf_t, feat_pad, inv_w2, inv_b2,
                                                g3, b3, m3, v3, buf5);

    // 4. conv1x1 64->128 + deterministic pool partials (into dead feat_pad)
    k_conv3<<<dim3(NBX, C0 / 16), 256, 0, stream>>>(buf5, w3, buf6, parts);

    // 5. SE MLP (reduces partials in fixed order)
    k_se<<<1, C0, 0, stream>>>(parts, se_w1, se_b1, se_w2, se_b2, scale);

    // 6. out = buf6 * scale + x
    k_final<<<(C0 * NPIX / 4) / 256, 256, 0, stream>>>(buf6, scale, x, out);
}

// Round 9
// 128.660 us; speedup vs baseline: 1.1506x; 1.1506x over previous
//
#include <hip/hip_runtime.h>
#include <math.h>

#define HPIX 160
#define WPIX 160
#define NPIX 25600      // 160*160
#define C0   128
#define CM   64
#define MID  16
#define KK   11
#define KK2  121
#define PAD  5
#define PADW 176        // 160 + 2*5, rounded up to 16 for row alignment
#define PADH 170
#define CHP  (PADH*PADW)   // 29920 floats per padded channel
#define NBX  (NPIX/256)    // 100 pixel-blocks for conv kernels
#define BN_EPS 1e-5f

__device__ __forceinline__ float elu_f(float y) { return y > 0.f ? y : expm1f(y); }

// ---------------- act = elu(bn1(x)), vectorized float4 ----------------
__global__ __launch_bounds__(256) void k_act(
        const float* __restrict__ x,
        const float* __restrict__ g1, const float* __restrict__ b1,
        const float* __restrict__ m1, const float* __restrict__ v1,
        float* __restrict__ act) {
    int i4 = blockIdx.x * 256 + threadIdx.x;
    int c = i4 / (NPIX / 4);
    float inv  = g1[c] * rsqrtf(v1[c] + BN_EPS);
    float beta = b1[c] - m1[c] * inv;
    float4 xv = ((const float4*)x)[i4];
    float4 o;
    o.x = elu_f(fmaf(xv.x, inv, beta));
    o.y = elu_f(fmaf(xv.y, inv, beta));
    o.z = elu_f(fmaf(xv.z, inv, beta));
    o.w = elu_f(fmaf(xv.w, inv, beta));
    ((float4*)act)[i4] = o;
}

// ---------------- conv1 (R6-proven form: scalar/uniform weight loads) -------
// grid (NBX, CM/16), block 256. Thread: 1 pixel, 16 output channels.
__global__ __launch_bounds__(256, 4) void k_conv1(
        const float* __restrict__ act, const float* __restrict__ w1,
        const float* __restrict__ g2, const float* __restrict__ b2,
        const float* __restrict__ m2, const float* __restrict__ v2,
        float* __restrict__ feat_pad) {
    const int tid = threadIdx.x;
    const int p   = blockIdx.x * 256 + tid;
    const int oc0 = blockIdx.y * 16;
    const float* wbase = w1 + oc0 * C0;

    float acc[16] = {0,0,0,0,0,0,0,0,0,0,0,0,0,0,0,0};
    #pragma unroll 4
    for (int k = 0; k < C0; ++k) {
        float a = act[k * NPIX + p];
        #pragma unroll
        for (int j = 0; j < 16; ++j)
            acc[j] = fmaf(wbase[j * C0 + k], a, acc[j]);
    }

    const int h = p / WPIX, w = p % WPIX;
    const int off = (h + PAD) * PADW + (w + PAD);
    #pragma unroll
    for (int j = 0; j < 16; ++j) {
        int c = oc0 + j;
        float inv = g2[c] * rsqrtf(v2[c] + BN_EPS);
        float y = acc[j] * inv + (b2[c] - m2[c] * inv);
        feat_pad[c * CHP + off] = elu_f(y);
    }
}

// ---------------- conv_t (R6-proven form) -----------------------------------
// grid (NBX, MID/4), block 256. Thread: 1 pixel, 4 output channels.
__global__ __launch_bounds__(256, 4) void k_conv_t(
        const float* __restrict__ feat_pad, const float* __restrict__ wt,
        const float* __restrict__ g, const float* __restrict__ b,
        const float* __restrict__ m, const float* __restrict__ v,
        float* __restrict__ t) {
    const int tid = threadIdx.x;
    const int p   = blockIdx.x * 256 + tid;
    const int oc0 = blockIdx.y * 4;
    const int h = p / WPIX, w = p % WPIX;
    const int off = (h + PAD) * PADW + (w + PAD);

    float acc[4] = {0,0,0,0};
    #pragma unroll 8
    for (int k = 0; k < CM; ++k) {
        float a = feat_pad[k * CHP + off];
        #pragma unroll
        for (int j = 0; j < 4; ++j)
            acc[j] = fmaf(wt[(oc0 + j) * CM + k], a, acc[j]);
    }
    #pragma unroll
    for (int j = 0; j < 4; ++j) {
        int c = oc0 + j;
        float inv = g[c] * rsqrtf(v[c] + BN_EPS);
        t[c * NPIX + p] = fmaxf(acc[j] * inv + (b[c] - m[c] * inv), 0.f);
    }
}

// ---------------- involution: kh-split wk-gen + weighted sum + bn3 + elu ----
// Block 128 threads, 16 px (one row) x 64 channels.
// LDS halved via 2 kh-chunks (0..4, 5..10): 17.9 KB -> 9 blocks/CU resident,
// so all 6.25 blocks/CU run in ONE dispatch round (R8's 32KB gave 2 rounds).
// Phase 3: thread = 4 px x 2 ch -> each wk ds_read_b128 feeds 8 FMAs.
__global__ __launch_bounds__(128, 4) void k_involution(
        const float* __restrict__ t, const float* __restrict__ feat_pad,
        const float* __restrict__ inv_w2, const float* __restrict__ inv_b2,
        const float* __restrict__ g3, const float* __restrict__ b3,
        const float* __restrict__ m3, const float* __restrict__ v3,
        float* __restrict__ out) {
    __shared__ float s_wk[4 * 66 * 16];   // max chunk: 4 groups x 66 x 16 px
    __shared__ float s_t[MID * 16];

    // T1 XCD swizzle: gridDim.x = 1600 (divisible by 8) -> bijective.
    const int q   = gridDim.x >> 3;
    const int b   = blockIdx.x;
    const int bid = (b & 7) * q + (b >> 3);

    const int tid = threadIdx.x;      // 0..127
    const int p0  = bid * 16;         // 16 consecutive px, same image row
    const int px  = tid & 15;
    const int jb  = tid >> 4;         // 0..7

    s_t[tid]       = t[(tid >> 4) * NPIX + p0 + px];
    s_t[tid + 128] = t[((tid >> 4) + 8) * NPIX + p0 + px];
    __syncthreads();

    const float tr0  = s_t[0*16+px],  tr1  = s_t[1*16+px];
    const float tr2  = s_t[2*16+px],  tr3  = s_t[3*16+px];
    const float tr4  = s_t[4*16+px],  tr5  = s_t[5*16+px];
    const float tr6  = s_t[6*16+px],  tr7  = s_t[7*16+px];
    const float tr8  = s_t[8*16+px],  tr9  = s_t[9*16+px];
    const float tr10 = s_t[10*16+px], tr11 = s_t[11*16+px];
    const float tr12 = s_t[12*16+px], tr13 = s_t[13*16+px];
    const float tr14 = s_t[14*16+px], tr15 = s_t[15*16+px];

#define WK_DOT(JSRC, DST) { \
    const float4* wrow_ = (const float4*)(inv_w2 + (JSRC) * MID); \
    float4 w0_ = wrow_[0], w1_ = wrow_[1], w2_ = wrow_[2], w3_ = wrow_[3]; \
    float lo_ = inv_b2[JSRC], hi_ = 0.f; \
    lo_ = fmaf(w0_.x, tr0,  lo_); lo_ = fmaf(w0_.y, tr1,  lo_); \
    lo_ = fmaf(w0_.z, tr2,  lo_); lo_ = fmaf(w0_.w, tr3,  lo_); \
    lo_ = fmaf(w1_.x, tr4,  lo_); lo_ = fmaf(w1_.y, tr5,  lo_); \
    lo_ = fmaf(w1_.z, tr6,  lo_); lo_ = fmaf(w1_.w, tr7,  lo_); \
    hi_ = fmaf(w2_.x, tr8,  hi_); hi_ = fmaf(w2_.y, tr9,  hi_); \
    hi_ = fmaf(w2_.z, tr10, hi_); hi_ = fmaf(w2_.w, tr11, hi_); \
    hi_ = fmaf(w3_.x, tr12, hi_); hi_ = fmaf(w3_.y, tr13, hi_); \
    hi_ = fmaf(w3_.z, tr14, hi_); hi_ = fmaf(w3_.w, tr15, hi_); \
    s_wk[(DST) * 16 + px] = lo_ + hi_; }

    // phase-3 geometry (fixed across chunks)
    const int tx = tid & 3;
    const int cp = tid >> 2;          // 0..31
    const int c0 = cp * 2;
    const int g  = c0 >> 4;
    const int h  = p0 / WPIX;
    const int wb = (p0 % WPIX) + tx * 4;
    const float* f0b = feat_pad + c0 * CHP + h * PADW + wb;
    const float* f1b = f0b + CHP;

    float a00 = 0.f, a01 = 0.f, a02 = 0.f, a03 = 0.f;
    float a10 = 0.f, a11 = 0.f, a12 = 0.f, a13 = 0.f;

    // ================= chunk A: kh 0..4 (CPG=55, j_local 0..54) ============
    for (int jj = jb; jj < 220; jj += 16) {
        int gA = jj / 55, jlA = jj - gA * 55;
        WK_DOT(gA * 121 + jlA, jj);
        int jj2 = jj + 8;
        if (jj2 < 220) {
            int gB = jj2 / 55, jlB = jj2 - gB * 55;
            WK_DOT(gB * 121 + jlB, jj2);
        }
    }
    __syncthreads();

    #pragma unroll 2
    for (int kh = 0; kh < 5; ++kh) {
        const float4* p0f = (const float4*)(f0b + kh * PADW);
        float4 A0 = p0f[0], B0 = p0f[1], Cq0 = p0f[2], D0 = p0f[3];
        const float4* p1f = (const float4*)(f1b + kh * PADW);
        float4 A1 = p1f[0], B1 = p1f[1], Cq1 = p1f[2], D1 = p1f[3];
        float f0[16] = {A0.x,A0.y,A0.z,A0.w, B0.x,B0.y,B0.z,B0.w,
                        Cq0.x,Cq0.y,Cq0.z,Cq0.w, D0.x,D0.y,D0.z,D0.w};
        float f1[16] = {A1.x,A1.y,A1.z,A1.w, B1.x,B1.y,B1.z,B1.w,
                        Cq1.x,Cq1.y,Cq1.z,Cq1.w, D1.x,D1.y,D1.z,D1.w};
        const float* wr = s_wk + (g * 55 + kh * 11) * 16 + tx * 4;
        #pragma unroll
        for (int kw = 0; kw < KK; ++kw) {
            float4 wv = *(const float4*)(wr + kw * 16);
            a00 = fmaf(wv.x, f0[kw + 0], a00);
            a01 = fmaf(wv.y, f0[kw + 1], a01);
            a02 = fmaf(wv.z, f0[kw + 2], a02);
            a03 = fmaf(wv.w, f0[kw + 3], a03);
            a10 = fmaf(wv.x, f1[kw + 0], a10);
            a11 = fmaf(wv.y, f1[kw + 1], a11);
            a12 = fmaf(wv.z, f1[kw + 2], a12);
            a13 = fmaf(wv.w, f1[kw + 3], a13);
        }
    }
    __syncthreads();

    // ================= chunk B: kh 5..10 (CPG=66, j_local 55..120) =========
    for (int jj = jb; jj < 264; jj += 16) {
        int gA = jj / 66, jlA = jj - gA * 66;
        WK_DOT(gA * 121 + 55 + jlA, jj);
        int jj2 = jj + 8;
        if (jj2 < 264) {
            int gB = jj2 / 66, jlB = jj2 - gB * 66;
            WK_DOT(gB * 121 + 55 + jlB, jj2);
        }
    }
    __syncthreads();

    #pragma unroll 2
    for (int kh = 5; kh < 11; ++kh) {
        const float4* p0f = (const float4*)(f0b + kh * PADW);
        float4 A0 = p0f[0], B0 = p0f[1], Cq0 = p0f[2], D0 = p0f[3];
        const float4* p1f = (const float4*)(f1b + kh * PADW);
        float4 A1 = p1f[0], B1 = p1f[1], Cq1 = p1f[2], D1 = p1f[3];
        float f0[16] = {A0.x,A0.y,A0.z,A0.w, B0.x,B0.y,B0.z,B0.w,
                        Cq0.x,Cq0.y,Cq0.z,Cq0.w, D0.x,D0.y,D0.z,D0.w};
        float f1[16] = {A1.x,A1.y,A1.z,A1.w, B1.x,B1.y,B1.z,B1.w,
                        Cq1.x,Cq1.y,Cq1.z,Cq1.w, D1.x,D1.y,D1.z,D1.w};
        const float* wr = s_wk + (g * 66 + (kh - 5) * 11) * 16 + tx * 4;
        #pragma unroll
        for (int kw = 0; kw < KK; ++kw) {
            float4 wv = *(const float4*)(wr + kw * 16);
            a00 = fmaf(wv.x, f0[kw + 0], a00);
            a01 = fmaf(wv.y, f0[kw + 1], a01);
            a02 = fmaf(wv.z, f0[kw + 2], a02);
            a03 = fmaf(wv.w, f0[kw + 3], a03);
            a10 = fmaf(wv.x, f1[kw + 0], a10);
            a11 = fmaf(wv.y, f1[kw + 1], a11);
            a12 = fmaf(wv.z, f1[kw + 2], a12);
            a13 = fmaf(wv.w, f1[kw + 3], a13);
        }
    }
#undef WK_DOT

    {
        float inv  = g3[c0] * rsqrtf(v3[c0] + BN_EPS);
        float beta = b3[c0] - m3[c0] * inv;
        float4 o;
        o.x = elu_f(fmaf(a00, inv, beta));
        o.y = elu_f(fmaf(a01, inv, beta));
        o.z = elu_f(fmaf(a02, inv, beta));
        o.w = elu_f(fmaf(a03, inv, beta));
        *(float4*)(out + c0 * NPIX + p0 + tx * 4) = o;
    }
    {
        int c1 = c0 + 1;
        float inv  = g3[c1] * rsqrtf(v3[c1] + BN_EPS);
        float beta = b3[c1] - m3[c1] * inv;
        float4 o;
        o.x = elu_f(fmaf(a10, inv, beta));
        o.y = elu_f(fmaf(a11, inv, beta));
        o.z = elu_f(fmaf(a12, inv, beta));
        o.w = elu_f(fmaf(a13, inv, beta));
        *(float4*)(out + c1 * NPIX + p0 + tx * 4) = o;
    }
}

// ---------------- conv3 (R6-proven form) + deterministic partials -----------
// grid (NBX, C0/16). Thread: 1 pixel, 16 output channels.
__global__ __launch_bounds__(256, 4) void k_conv3(
        const float* __restrict__ in, const float* __restrict__ w,
        float* __restrict__ out, float* __restrict__ parts) {
    const int tid = threadIdx.x;
    const int p   = blockIdx.x * 256 + tid;
    const int oc0 = blockIdx.y * 16;
    const float* wbase = w + oc0 * CM;

    float acc[16] = {0,0,0,0,0,0,0,0,0,0,0,0,0,0,0,0};
    #pragma unroll 4
    for (int k = 0; k < CM; ++k) {
        float a = in[k * NPIX + p];
        #pragma unroll
        for (int j = 0; j < 16; ++j)
            acc[j] = fmaf(wbase[j * CM + k], a, acc[j]);
    }
    #pragma unroll
    for (int j = 0; j < 16; ++j)
        out[(oc0 + j) * NPIX + p] = acc[j];

    __shared__ float s_red[16][4];
    const int lane = tid & 63, wid = tid >> 6;
    #pragma unroll
    for (int j = 0; j < 16; ++j) {
        float s = acc[j];
        #pragma unroll
        for (int off = 32; off; off >>= 1) s += __shfl_down(s, off);
        if (lane == 0) s_red[j][wid] = s;
    }
    __syncthreads();
    if (tid < 16) {
        float s = s_red[tid][0] + s_red[tid][1] + s_red[tid][2] + s_red[tid][3];
        parts[(oc0 + tid) * NBX + blockIdx.x] = s;   // deterministic write
    }
}

// ---------------- SE MLP: reduce partials -> 128->8 relu -> 8->128 sigmoid --
__global__ void k_se(const float* __restrict__ parts,
                     const float* __restrict__ w1, const float* __restrict__ b1,
                     const float* __restrict__ w2, const float* __restrict__ b2,
                     float* __restrict__ scale) {
    __shared__ float s_p[C0];
    __shared__ float s_h[8];
    int tid = threadIdx.x;
    float s = 0.f;
    for (int i = 0; i < NBX; ++i) s += parts[tid * NBX + i];  // fixed order
    s_p[tid] = s * (1.f / NPIX);
    __syncthreads();
    if (tid < 8) {
        float acc = b1[tid];
        for (int c = 0; c < C0; ++c) acc = fmaf(w1[tid * C0 + c], s_p[c], acc);
        s_h[tid] = fmaxf(acc, 0.f);
    }
    __syncthreads();
    float acc = b2[tid];
    #pragma unroll
    for (int j = 0; j < 8; ++j) acc = fmaf(w2[tid * 8 + j], s_h[j], acc);
    scale[tid] = 1.f / (1.f + expf(-acc));
}

// ---------------- Final: out = pre * scale[c] + x, float4 ----------------
__global__ __launch_bounds__(256) void k_final(
        const float* __restrict__ pre, const float* __restrict__ scale,
        const float* __restrict__ x, float* __restrict__ out) {
    int i4 = blockIdx.x * 256 + threadIdx.x;
    int c = i4 / (NPIX / 4);
    float sc = scale[c];
    float4 pv = ((const float4*)pre)[i4];
    float4 xv = ((const float4*)x)[i4];
    float4 o;
    o.x = fmaf(pv.x, sc, xv.x);
    o.y = fmaf(pv.y, sc, xv.y);
    o.z = fmaf(pv.z, sc, xv.z);
    o.w = fmaf(pv.w, sc, xv.w);
    ((float4*)out)[i4] = o;
}

extern "C" void kernel_launch(void* const* d_in, const int* in_sizes, int n_in,
                              void* d_out, int out_size, void* d_ws, size_t ws_size,
                              hipStream_t stream) {
    const float* x      = (const float*)d_in[0];
    const float* g1     = (const float*)d_in[1];
    const float* b1     = (const float*)d_in[2];
    const float* m1     = (const float*)d_in[3];
    const float* v1     = (const float*)d_in[4];
    const float* w1     = (const float*)d_in[5];
    const float* g2     = (const float*)d_in[6];
    const float* b2     = (const float*)d_in[7];
    const float* m2     = (const float*)d_in[8];
    const float* v2     = (const float*)d_in[9];
    const float* inv_w1 = (const float*)d_in[10];
    const float* ig     = (const float*)d_in[11];
    const float* ib     = (const float*)d_in[12];
    const float* im     = (const float*)d_in[13];
    const float* iv     = (const float*)d_in[14];
    const float* inv_w2 = (const float*)d_in[15];
    const float* inv_b2 = (const float*)d_in[16];
    const float* g3     = (const float*)d_in[17];
    const float* b3     = (const float*)d_in[18];
    const float* m3     = (const float*)d_in[19];
    const float* v3     = (const float*)d_in[20];
    const float* w3     = (const float*)d_in[21];
    const float* se_w1  = (const float*)d_in[22];
    const float* se_b1  = (const float*)d_in[23];
    const float* se_w2  = (const float*)d_in[24];
    const float* se_b2  = (const float*)d_in[25];
    float* out = (float*)d_out;

    float* ws       = (float*)d_ws;
    float* act      = ws;                        // 128*25600 (elu(bn1(x)))
    float* feat_pad = act + C0 * NPIX;           // 64 * 29920 (zero-padded)
    float* buf_t    = feat_pad + CM * CHP;       // 16 * 25600
    float* buf5     = act;                       // alias: act dead after conv1
    float* buf6     = buf_t + MID * NPIX;        // 128 * 25600
    float* parts    = feat_pad;                  // alias: feat dead after invol
    float* scale    = buf6 + C0 * NPIX;          // 128

    // zero padded-feat border (every call; conv1 rewrites the interior)
    hipMemsetAsync(feat_pad, 0, (size_t)CM * CHP * sizeof(float), stream);

    // 1. act = elu(bn1(x)) once
    k_act<<<(C0 * NPIX / 4) / 256, 256, 0, stream>>>(x, g1, b1, m1, v1, act);

    // 2. conv1x1 128->64 + bn2+elu, into padded layout
    k_conv1<<<dim3(NBX, CM / 16), 256, 0, stream>>>(
        act, w1, g2, b2, m2, v2, feat_pad);

    // 3a. involution reduce: conv1x1 64->16 + bn + relu
    k_conv_t<<<dim3(NBX, MID / 4), 256, 0, stream>>>(
        feat_pad, inv_w1, ig, ib, im, iv, buf_t);

    // 3b. involution (kh-split wk-gen + weighted patch sum) + bn3 + elu
    k_involution<<<NPIX / 16, 128, 0, stream>>>(buf_t, feat_pad, inv_w2, inv_b2,
                                                g3, b3, m3, v3, buf5);

    // 4. conv1x1 64->128 + deterministic pool partials (into dead feat_pad)
    k_conv3<<<dim3(NBX, C0 / 16), 256, 0, stream>>>(buf5, w3, buf6, parts);

    // 5. SE MLP (reduces partials in fixed order)
    k_se<<<1, C0, 0, stream>>>(parts, se_w1, se_b1, se_w2, se_b2, scale);

    // 6. out = buf6 * scale + x
    k_final<<<(C0 * NPIX / 4) / 256, 256, 0, stream>>>(buf6, scale, x, out);
}